// Round 4
// baseline (156.917 us; speedup 1.0000x reference)
//
#include <hip/hip_runtime.h>

#define NB 32
#define CC 64
#define CE 96      // extended cols: 0..63 xw, 64..79 x1(alpha), 80..95 x2(phi)
#define TT 300
#define VV 25
#define HH 16
#define TPOUT 150
#define KH 4       // kernel//2
#define TC 4       // timesteps per k1 block

#define TPC 25     // selected rows per k2 chunk
#define NCHUNK 6
#define ROWS_MAX 57
#define SLE 100    // k2 band LDS leading dim (400B rows, 16B-aligned)
#define SXLD 100   // k1 sx leading dim

// ---------------- Kernel 0: Wext = [W | W@alphaT | W@phiT]  (64 x 96) --------
__global__ __launch_bounds__(256) void k0_wext(const float* __restrict__ W,
                                               const float* __restrict__ alpha,
                                               const float* __restrict__ phi,
                                               float* __restrict__ Wext) {
    __shared__ float sW[64][64];
    __shared__ float sA[32][64];   // rows 0..15 alpha, 16..31 phi
    const int tid = threadIdx.x;
    for (int i = tid; i < 1024; i += 256)
        reinterpret_cast<float4*>(&sW[0][0])[i] = reinterpret_cast<const float4*>(W)[i];
    for (int i = tid; i < 512; i += 256) {
        float4 v = (i < 256) ? reinterpret_cast<const float4*>(alpha)[i]
                             : reinterpret_cast<const float4*>(phi)[i - 256];
        reinterpret_cast<float4*>(&sA[0][0])[i] = v;
    }
    __syncthreads();
    // copy W into cols 0..63
    for (int i = tid; i < 1024; i += 256) {
        int ci = i >> 4, q = i & 15;
        reinterpret_cast<float4*>(&Wext[(size_t)ci * CE])[q] =
            reinterpret_cast<const float4*>(&sW[ci][0])[q];
    }
    // dots into cols 64..95
    for (int i = tid; i < 2048; i += 256) {
        int ci = i >> 5, j = i & 31;
        const float4* a = reinterpret_cast<const float4*>(&sW[ci][0]);
        const float4* b = reinterpret_cast<const float4*>(&sA[j][0]);
        float acc = 0.f;
#pragma unroll
        for (int q = 0; q < 16; ++q) {
            float4 u = a[q], w = b[q];
            acc += u.x * w.x + u.y * w.y + u.z * w.z + u.w * w.w;
        }
        Wext[(size_t)ci * CE + 64 + j] = acc;
    }
}

// ---------------- Kernel 1: xwe[r][t][0..95] = x-slice @ Wext ---------------
// Broadcast-GEMM: lane = out column; x read as wave-uniform float4 broadcasts.
__global__ __launch_bounds__(256) void k1_xw(const float* __restrict__ x,
                                             const float* __restrict__ Wext,
                                             float* __restrict__ xwe) {
    __shared__ float sW[64][CE];     // [ci][col]
    __shared__ float sx[64][SXLD];   // [ci][tv], tv = tloc*25+v (100 used)
    const int n  = blockIdx.y;
    const int t0 = blockIdx.x * TC;
    const int tid = threadIdx.x;

    for (int i = tid; i < 64 * 24; i += 256)      // 6144 floats, contiguous
        reinterpret_cast<float4*>(&sW[0][0])[i] = reinterpret_cast<const float4*>(Wext)[i];
    const float* xb = x + (size_t)n * CC * TT * VV + (size_t)t0 * VV;
    for (int i = tid; i < 64 * 25; i += 256) {
        int ci = i / 25, q = i - ci * 25;
        reinterpret_cast<float4*>(&sx[ci][0])[q] =
            *reinterpret_cast<const float4*>(&xb[(size_t)ci * TT * VV + q * 4]);
    }
    __syncthreads();

    const int lane  = tid & 63;
    const int wv    = tid >> 6;
    const int wbase = 28 * wv;                    // wave tv base: 0,28,56,84
    const size_t rbase = (size_t)n * VV;

    // ---- pass 1: cols 0..63 (lane = col), 28 tvs per wave ----
    {
        int cols[7];
#pragma unroll
        for (int g = 0; g < 7; ++g) cols[g] = min(wbase + 4 * g, 96);
        float acc[28];
#pragma unroll
        for (int j = 0; j < 28; ++j) acc[j] = 0.f;
        for (int ci = 0; ci < 64; ++ci) {
            float w = sW[ci][lane];
            float4 xq[7];
#pragma unroll
            for (int g = 0; g < 7; ++g)
                xq[g] = *reinterpret_cast<const float4*>(&sx[ci][cols[g]]);
#pragma unroll
            for (int j = 0; j < 28; ++j) {
                float xv = (j & 3) == 0 ? xq[j >> 2].x : (j & 3) == 1 ? xq[j >> 2].y
                         : (j & 3) == 2 ? xq[j >> 2].z : xq[j >> 2].w;
                acc[j] = fmaf(w, xv, acc[j]);
            }
        }
#pragma unroll
        for (int j = 0; j < 28; ++j) {
            int tv = wbase + j;
            if (tv < 100) {
                int tloc = tv / 25, v = tv - 25 * tloc;
                xwe[((rbase + v) * TT + (t0 + tloc)) * CE + lane] = acc[j];
            }
        }
    }

    // ---- pass 2: cols 64..95; lane = (tv-half, c32) ----
    {
        const int c32 = lane & 31, tvh = lane >> 5;
        const int cb2 = wbase + 16 * tvh;
        int cols2[4];
#pragma unroll
        for (int g = 0; g < 4; ++g) cols2[g] = min(cb2 + 4 * g, 96);
        float acc2[16];
#pragma unroll
        for (int j = 0; j < 16; ++j) acc2[j] = 0.f;
        for (int ci = 0; ci < 64; ++ci) {
            float w2 = sW[ci][64 + c32];
            float4 yq[4];
#pragma unroll
            for (int g = 0; g < 4; ++g)
                yq[g] = *reinterpret_cast<const float4*>(&sx[ci][cols2[g]]);
#pragma unroll
            for (int j = 0; j < 16; ++j) {
                float xv = (j & 3) == 0 ? yq[j >> 2].x : (j & 3) == 1 ? yq[j >> 2].y
                         : (j & 3) == 2 ? yq[j >> 2].z : yq[j >> 2].w;
                acc2[j] = fmaf(w2, xv, acc2[j]);
            }
        }
#pragma unroll
        for (int j = 0; j < 16; ++j) {
            int tv = cb2 + j;
            bool ok = (tvh == 0 || j < 12) && (tv < 100);
            if (ok) {
                int tloc = tv / 25, v = tv - 25 * tloc;
                xwe[((rbase + v) * TT + (t0 + tloc)) * CE + 64 + c32] = acc2[j];
            }
        }
    }
}

// ---------------- Kernel 1b: ssum[r][c] = sum_t xwe[r][t][c], c<64 -----------
__global__ __launch_bounds__(256) void k1b_colsum(const float* __restrict__ xwe,
                                                  float* __restrict__ ssum) {
    __shared__ float sred[256];
    const int r = blockIdx.x;
    const float* p = xwe + (size_t)r * TT * CE;
    const int c = threadIdx.x & 63, g = threadIdx.x >> 6;
    float acc = 0.f;
    for (int t = g; t < TT; t += 4) acc += p[(size_t)t * CE + c];
    sred[threadIdx.x] = acc;
    __syncthreads();
    if (threadIdx.x < 64)
        ssum[(size_t)r * CC + threadIdx.x] =
            sred[threadIdx.x] + sred[threadIdx.x + 64] +
            sred[threadIdx.x + 128] + sred[threadIdx.x + 192];
}

// ---------------- Kernel 2: banded attention, one (chunk, r) per block -------
__global__ __launch_bounds__(256) void k2_attn(const float* __restrict__ xwe,
                                               const float* __restrict__ ssum,
                                               float* __restrict__ tmp) {
    const int ch = blockIdx.x;    // 0..5
    const int r  = blockIdx.y;    // n*25 + v

    __shared__ __align__(16) float sxe[ROWS_MAX][SLE];  // band rows, 96 cols
    __shared__ float sss[CC];
    __shared__ float sscore[TPC][9];
    __shared__ float scoef[TPC][10];

    const int tid = threadIdx.x;
    const int tp0 = ch * TPC;
    const int s_lo = max(0, 2 * tp0 - KH);
    const int s_hi = min(TT - 1, 2 * (tp0 + TPC - 1) + KH);
    const int rows = s_hi - s_lo + 1;

    const float* base = xwe + ((size_t)r * TT + s_lo) * CE;
    for (int i = tid; i < rows * 24; i += 256) {
        int row = i / 24, q = i - row * 24;
        *reinterpret_cast<float4*>(&sxe[row][q * 4]) =
            *reinterpret_cast<const float4*>(&base[(size_t)row * CE + q * 4]);
    }
    if (tid < CC) sss[tid] = ssum[(size_t)r * CC + tid];
    __syncthreads();

    // band scores: x1 = cols 64..79 of row t; x2 = cols 80..95 of row s
    if (tid < TPC * 9) {
        int tpl = tid / 9, k = tid - tpl * 9;
        int t = 2 * (tp0 + tpl);
        int s = t - KH + k;
        float sc = 0.f;
        if (s >= 0 && s < TT) {
            const float4* x1 = reinterpret_cast<const float4*>(&sxe[t - s_lo][64]);
            const float4* x2 = reinterpret_cast<const float4*>(&sxe[s - s_lo][80]);
#pragma unroll
            for (int q = 0; q < 4; ++q) {
                float4 a = x1[q], b = x2[q];
                sc += a.x * b.x + a.y * b.y + a.z * b.z + a.w * b.w;
            }
        }
        sscore[tpl][k] = sc;
    }
    __syncthreads();

    // softmax coefficients (out-of-band zeros fold analytically)
    if (tid < TPC) {
        int tpl = tid;
        int t = 2 * (tp0 + tpl);
        float m = 0.f;
        int nb = 0;
#pragma unroll
        for (int k = 0; k < 9; ++k) {
            int s = t - KH + k;
            if (s >= 0 && s < TT) { nb++; m = fmaxf(m, sscore[tpl][k]); }
        }
        float wbg = __expf(-m);
        float Z = (float)(TT - nb) * wbg;
        float e[9];
#pragma unroll
        for (int k = 0; k < 9; ++k) {
            int s = t - KH + k;
            float ek = (s >= 0 && s < TT) ? __expf(sscore[tpl][k] - m) : 0.f;
            e[k] = ek;
            Z += ek;
        }
        float inv = 1.f / Z;
#pragma unroll
        for (int k = 0; k < 9; ++k) {
            int s = t - KH + k;
            scoef[tpl][k] = (s >= 0 && s < TT) ? (e[k] - wbg) * inv : 0.f;
        }
        scoef[tpl][9] = wbg * inv;
    }
    __syncthreads();

    // tmp[r][tp][c] = cbg*ssum[c] + sum_k coef_k * xw_band[row][c]
    for (int i = tid; i < TPC * CC; i += 256) {
        int tpl = i >> 6, c = i & 63;
        int t = 2 * (tp0 + tpl);
        int row0 = t - KH - s_lo;
        float val = scoef[tpl][9] * sss[c];
#pragma unroll
        for (int k = 0; k < 9; ++k) {
            int row = row0 + k;
            row = min(max(row, 0), rows - 1);   // coef is 0 for invalid slots
            val += scoef[tpl][k] * sxe[row][c];
        }
        tmp[((size_t)r * TPOUT + (tp0 + tpl)) * CC + c] = val;
    }
}

// ---------------- Kernel 3: tmp[n][v][tp][c] -> out[n][c][tp][v] -------------
#define TPT 5
__global__ __launch_bounds__(256) void k3_transpose(const float* __restrict__ tmp,
                                                    float* __restrict__ out) {
    __shared__ float tile[VV][TPT][65];
    const int n = blockIdx.y;
    const int tp0 = blockIdx.x * TPT;
    const int tid = threadIdx.x;

    const float* src = tmp + (size_t)n * (VV * TPOUT * CC);
    for (int i = tid; i < VV * TPT * CC; i += 256) {
        int v = i / (TPT * CC);
        int rem = i - v * (TPT * CC);
        int tpl = rem >> 6, c = rem & 63;
        tile[v][tpl][c] = src[((size_t)v * TPOUT + tp0 + tpl) * CC + c];
    }
    __syncthreads();
    float* dst = out + (size_t)n * (CC * TPOUT * VV);
    for (int j = tid; j < CC * TPT * VV; j += 256) {
        int c = j / (TPT * VV);
        int rem = j - c * (TPT * VV);
        int tpl = rem / VV, v = rem - tpl * VV;
        dst[(size_t)c * (TPOUT * VV) + (tp0 + tpl) * VV + v] = tile[v][tpl][c];
    }
}

extern "C" void kernel_launch(void* const* d_in, const int* in_sizes, int n_in,
                              void* d_out, int out_size, void* d_ws, size_t ws_size,
                              hipStream_t stream) {
    const float* x     = (const float*)d_in[0];
    const float* W     = (const float*)d_in[1];
    const float* alpha = (const float*)d_in[2];
    const float* phi   = (const float*)d_in[3];
    float* out = (float*)d_out;

    float* xwe  = (float*)d_ws;                         // 800*300*96 = 23,040,000 f
    float* tmp  = xwe + (size_t)800 * 300 * CE;         // 800*150*64 =  7,680,000 f
    float* ssum = tmp + (size_t)800 * 150 * 64;         // 800*64     =     51,200 f
    float* Wext = ssum + (size_t)800 * 64;              // 64*96      =      6,144 f
                                                        // total ~123.1 MB

    k0_wext<<<1, 256, 0, stream>>>(W, alpha, phi, Wext);
    dim3 g1(TT / TC, NB);
    k1_xw<<<g1, 256, 0, stream>>>(x, Wext, xwe);
    k1b_colsum<<<NB * VV, 256, 0, stream>>>(xwe, ssum);
    dim3 g2(NCHUNK, NB * VV);
    k2_attn<<<g2, 256, 0, stream>>>(xwe, ssum, tmp);
    dim3 g3(TPOUT / TPT, NB);
    k3_transpose<<<g3, 256, 0, stream>>>(tmp, out);
}

// Round 5
// 118.528 us; speedup vs baseline: 1.3239x; 1.3239x over previous
//
#include <hip/hip_runtime.h>

#define NB 32
#define CC 64
#define CS 32      // score cols: 0..15 alpha(x1), 16..31 phi(x2)
#define TT 300
#define VV 25
#define HH 16
#define TPOUT 150
#define KH 4       // kernel//2
#define TC 4       // timesteps per k1 block

#define TPC 25     // selected rows per k2 chunk
#define NCHUNK 6
#define ROWS_MAX 57
#define SLV 68     // k2 value-band LDS leading dim
#define SLS 36     // k2 score-band LDS leading dim
#define K1LD 100   // k1 LDS leading dim (400B rows, 16B-aligned)

// ---------------- Kernel 0: Ws = [W@alphaT | W@phiT]  (64 x 32) --------------
__global__ __launch_bounds__(256) void k0_ws(const float* __restrict__ W,
                                             const float* __restrict__ alpha,
                                             const float* __restrict__ phi,
                                             float* __restrict__ Ws) {
    __shared__ float sW[64][64];
    __shared__ float sA[32][64];   // rows 0..15 alpha, 16..31 phi
    const int tid = threadIdx.x;
    for (int i = tid; i < 1024; i += 256)
        reinterpret_cast<float4*>(&sW[0][0])[i] = reinterpret_cast<const float4*>(W)[i];
    for (int i = tid; i < 512; i += 256) {
        float4 v = (i < 256) ? reinterpret_cast<const float4*>(alpha)[i]
                             : reinterpret_cast<const float4*>(phi)[i - 256];
        reinterpret_cast<float4*>(&sA[0][0])[i] = v;
    }
    __syncthreads();
    for (int i = tid; i < 2048; i += 256) {
        int ci = i >> 5, j = i & 31;
        const float4* a = reinterpret_cast<const float4*>(&sW[ci][0]);
        const float4* b = reinterpret_cast<const float4*>(&sA[j][0]);
        float acc = 0.f;
#pragma unroll
        for (int q = 0; q < 16; ++q) {
            float4 u = a[q], w = b[q];
            acc += u.x * w.x + u.y * w.y + u.z * w.z + u.w * w.w;
        }
        Ws[(size_t)ci * CS + j] = acc;
    }
}

// ---------------- Kernel 1: xwv/xws = x-slice @ [W | Ws] ---------------------
// 2D register tiling: thread tile = 5 tv x 8 col, 240 active threads.
__global__ __launch_bounds__(256) void k1_xw(const float* __restrict__ x,
                                             const float* __restrict__ W,
                                             const float* __restrict__ Ws,
                                             float* __restrict__ xwv,
                                             float* __restrict__ xws) {
    __shared__ float sW[64][K1LD];   // cols 0..63 = W, 64..95 = Ws
    __shared__ float sx[64][K1LD];   // [ci][tv], tv = tloc*25+v, 100 used
    const int n  = blockIdx.y;
    const int t0 = blockIdx.x * TC;
    const int tid = threadIdx.x;

    for (int i = tid; i < 1024; i += 256) {              // W cols 0..63
        int ci = i >> 4, q = i & 15;
        *reinterpret_cast<float4*>(&sW[ci][4 * q]) = reinterpret_cast<const float4*>(W)[i];
    }
    for (int i = tid; i < 512; i += 256) {               // Ws cols 64..95
        int ci = i >> 3, q = i & 7;
        *reinterpret_cast<float4*>(&sW[ci][64 + 4 * q]) = reinterpret_cast<const float4*>(Ws)[i];
    }
    const float* xb = x + (size_t)n * CC * TT * VV + (size_t)t0 * VV;
    for (int i = tid; i < 64 * 25; i += 256) {
        int ci = i / 25, q = i - ci * 25;
        *reinterpret_cast<float4*>(&sx[ci][4 * q]) =
            *reinterpret_cast<const float4*>(&xb[(size_t)ci * TT * VV + 4 * q]);
    }
    __syncthreads();

    if (tid < 240) {
        const int tvg  = tid / 12;        // 12 consecutive lanes share tvg (x broadcast)
        const int colg = tid % 12;
        const int tv0  = tvg * 5;
        const int col0 = colg * 8;        // colg<8 -> value cols, >=8 -> score cols

        float acc[5][8];
#pragma unroll
        for (int i = 0; i < 5; ++i)
#pragma unroll
            for (int j = 0; j < 8; ++j) acc[i][j] = 0.f;

#pragma unroll 4
        for (int ci = 0; ci < 64; ++ci) {
            float xr[5];
#pragma unroll
            for (int i = 0; i < 5; ++i) xr[i] = sx[ci][tv0 + i];
            float4 w0 = *reinterpret_cast<const float4*>(&sW[ci][col0]);
            float4 w1 = *reinterpret_cast<const float4*>(&sW[ci][col0 + 4]);
#pragma unroll
            for (int i = 0; i < 5; ++i) {
                acc[i][0] = fmaf(xr[i], w0.x, acc[i][0]);
                acc[i][1] = fmaf(xr[i], w0.y, acc[i][1]);
                acc[i][2] = fmaf(xr[i], w0.z, acc[i][2]);
                acc[i][3] = fmaf(xr[i], w0.w, acc[i][3]);
                acc[i][4] = fmaf(xr[i], w1.x, acc[i][4]);
                acc[i][5] = fmaf(xr[i], w1.y, acc[i][5]);
                acc[i][6] = fmaf(xr[i], w1.z, acc[i][6]);
                acc[i][7] = fmaf(xr[i], w1.w, acc[i][7]);
            }
        }

#pragma unroll
        for (int i = 0; i < 5; ++i) {
            int tv = tv0 + i;
            int tloc = tv / 25, v = tv - 25 * tloc;
            size_t row = (size_t)(n * VV + v) * TT + (t0 + tloc);
            float4 sA = {acc[i][0], acc[i][1], acc[i][2], acc[i][3]};
            float4 sB = {acc[i][4], acc[i][5], acc[i][6], acc[i][7]};
            if (colg < 8) {
                float* p = &xwv[row * CC + col0];
                *reinterpret_cast<float4*>(p)     = sA;
                *reinterpret_cast<float4*>(p + 4) = sB;
            } else {
                float* p = &xws[row * CS + (col0 - 64)];
                *reinterpret_cast<float4*>(p)     = sA;
                *reinterpret_cast<float4*>(p + 4) = sB;
            }
        }
    }
}

// ---------------- Kernel 1b: ssum[r][c] = sum_t xwv[r][t][c] -----------------
__global__ __launch_bounds__(256) void k1b_colsum(const float* __restrict__ xwv,
                                                  float* __restrict__ ssum) {
    __shared__ float sred[16][64];
    const int r = blockIdx.x;
    const float* p = xwv + (size_t)r * TT * CC;
    const int c4 = threadIdx.x & 15, g = threadIdx.x >> 4;
    float4 a = {0.f, 0.f, 0.f, 0.f};
    for (int t = g; t < TT; t += 16) {
        float4 v = *reinterpret_cast<const float4*>(&p[(size_t)t * CC + 4 * c4]);
        a.x += v.x; a.y += v.y; a.z += v.z; a.w += v.w;
    }
    *reinterpret_cast<float4*>(&sred[g][4 * c4]) = a;
    __syncthreads();
    if (threadIdx.x < 64) {
        float acc = 0.f;
#pragma unroll
        for (int g2 = 0; g2 < 16; ++g2) acc += sred[g2][threadIdx.x];
        ssum[(size_t)r * CC + threadIdx.x] = acc;
    }
}

// ---------------- Kernel 2: banded attention, one (chunk, r) per block -------
__global__ __launch_bounds__(256) void k2_attn(const float* __restrict__ xwv,
                                               const float* __restrict__ xws,
                                               const float* __restrict__ ssum,
                                               float* __restrict__ tmp) {
    const int ch = blockIdx.x;    // 0..5
    const int r  = blockIdx.y;    // n*25 + v

    __shared__ __align__(16) float sxv[ROWS_MAX][SLV];  // value cols
    __shared__ __align__(16) float sxs[ROWS_MAX][SLS];  // score cols
    __shared__ float sss[CC];
    __shared__ float sscore[TPC][9];
    __shared__ float scoef[TPC][10];

    const int tid = threadIdx.x;
    const int tp0 = ch * TPC;
    const int s_lo = max(0, 2 * tp0 - KH);
    const int s_hi = min(TT - 1, 2 * (tp0 + TPC - 1) + KH);
    const int rows = s_hi - s_lo + 1;

    const float* bv = xwv + ((size_t)r * TT + s_lo) * CC;
    for (int i = tid; i < rows * 16; i += 256) {
        int row = i >> 4, q = i & 15;
        *reinterpret_cast<float4*>(&sxv[row][4 * q]) =
            *reinterpret_cast<const float4*>(&bv[(size_t)row * CC + 4 * q]);
    }
    const float* bs = xws + ((size_t)r * TT + s_lo) * CS;
    for (int i = tid; i < rows * 8; i += 256) {
        int row = i >> 3, q = i & 7;
        *reinterpret_cast<float4*>(&sxs[row][4 * q]) =
            *reinterpret_cast<const float4*>(&bs[(size_t)row * CS + 4 * q]);
    }
    if (tid < CC) sss[tid] = ssum[(size_t)r * CC + tid];
    __syncthreads();

    // band scores: x1 = sxs[t][0..15], x2 = sxs[s][16..31]
    if (tid < TPC * 9) {
        int tpl = tid / 9, k = tid - tpl * 9;
        int t = 2 * (tp0 + tpl);
        int s = t - KH + k;
        float sc = 0.f;
        if (s >= 0 && s < TT) {
            const float4* x1 = reinterpret_cast<const float4*>(&sxs[t - s_lo][0]);
            const float4* x2 = reinterpret_cast<const float4*>(&sxs[s - s_lo][16]);
#pragma unroll
            for (int q = 0; q < 4; ++q) {
                float4 a = x1[q], b = x2[q];
                sc += a.x * b.x + a.y * b.y + a.z * b.z + a.w * b.w;
            }
        }
        sscore[tpl][k] = sc;
    }
    __syncthreads();

    // softmax coefficients (out-of-band zeros fold analytically)
    if (tid < TPC) {
        int tpl = tid;
        int t = 2 * (tp0 + tpl);
        float m = 0.f;
        int nb = 0;
#pragma unroll
        for (int k = 0; k < 9; ++k) {
            int s = t - KH + k;
            if (s >= 0 && s < TT) { nb++; m = fmaxf(m, sscore[tpl][k]); }
        }
        float wbg = __expf(-m);
        float Z = (float)(TT - nb) * wbg;
        float e[9];
#pragma unroll
        for (int k = 0; k < 9; ++k) {
            int s = t - KH + k;
            float ek = (s >= 0 && s < TT) ? __expf(sscore[tpl][k] - m) : 0.f;
            e[k] = ek;
            Z += ek;
        }
        float inv = 1.f / Z;
#pragma unroll
        for (int k = 0; k < 9; ++k) {
            int s = t - KH + k;
            scoef[tpl][k] = (s >= 0 && s < TT) ? (e[k] - wbg) * inv : 0.f;
        }
        scoef[tpl][9] = wbg * inv;
    }
    __syncthreads();

    // tmp[r][tp][c] = cbg*ssum[c] + sum_k coef_k * xwv_band[row][c]
    for (int i = tid; i < TPC * CC; i += 256) {
        int tpl = i >> 6, c = i & 63;
        int t = 2 * (tp0 + tpl);
        int row0 = t - KH - s_lo;
        float val = scoef[tpl][9] * sss[c];
#pragma unroll
        for (int k = 0; k < 9; ++k) {
            int row = row0 + k;
            row = min(max(row, 0), rows - 1);   // coef is 0 for invalid slots
            val += scoef[tpl][k] * sxv[row][c];
        }
        tmp[((size_t)r * TPOUT + (tp0 + tpl)) * CC + c] = val;
    }
}

// ---------------- Kernel 3: tmp[n][v][tp][c] -> out[n][c][tp][v] -------------
#define TPT 5
__global__ __launch_bounds__(256) void k3_transpose(const float* __restrict__ tmp,
                                                    float* __restrict__ out) {
    __shared__ float tile[VV][TPT][65];
    const int n = blockIdx.y;
    const int tp0 = blockIdx.x * TPT;
    const int tid = threadIdx.x;

    const float* src = tmp + (size_t)n * (VV * TPOUT * CC);
    for (int i = tid; i < VV * TPT * CC; i += 256) {
        int v = i / (TPT * CC);
        int rem = i - v * (TPT * CC);
        int tpl = rem >> 6, c = rem & 63;
        tile[v][tpl][c] = src[((size_t)v * TPOUT + tp0 + tpl) * CC + c];
    }
    __syncthreads();
    float* dst = out + (size_t)n * (CC * TPOUT * VV);
    for (int j = tid; j < CC * TPT * VV; j += 256) {
        int c = j / (TPT * VV);
        int rem = j - c * (TPT * VV);
        int tpl = rem / VV, v = rem - tpl * VV;
        dst[(size_t)c * (TPOUT * VV) + (tp0 + tpl) * VV + v] = tile[v][tpl][c];
    }
}

extern "C" void kernel_launch(void* const* d_in, const int* in_sizes, int n_in,
                              void* d_out, int out_size, void* d_ws, size_t ws_size,
                              hipStream_t stream) {
    const float* x     = (const float*)d_in[0];
    const float* W     = (const float*)d_in[1];
    const float* alpha = (const float*)d_in[2];
    const float* phi   = (const float*)d_in[3];
    float* out = (float*)d_out;

    float* xwv  = (float*)d_ws;                         // 800*300*64 = 15,360,000 f
    float* xws  = xwv + (size_t)800 * 300 * CC;         // 800*300*32 =  7,680,000 f
    float* tmp  = xws + (size_t)800 * 300 * CS;         // 800*150*64 =  7,680,000 f
    float* ssum = tmp + (size_t)800 * 150 * 64;         // 800*64     =     51,200 f
    float* Ws   = ssum + (size_t)800 * 64;              // 64*32      =      2,048 f
                                                        // total ~123 MB

    k0_ws<<<1, 256, 0, stream>>>(W, alpha, phi, Ws);
    dim3 g1(TT / TC, NB);
    k1_xw<<<g1, 256, 0, stream>>>(x, W, Ws, xwv, xws);
    k1b_colsum<<<NB * VV, 256, 0, stream>>>(xwv, ssum);
    dim3 g2(NCHUNK, NB * VV);
    k2_attn<<<g2, 256, 0, stream>>>(xwv, xws, ssum, tmp);
    dim3 g3(TPOUT / TPT, NB);
    k3_transpose<<<g3, 256, 0, stream>>>(tmp, out);
}